// Round 6
// baseline (436.948 us; speedup 1.0000x reference)
//
#include <hip/hip_runtime.h>

#define C_LAB 24
#define EDIM 16
#define PPIX (768 * 768)
#define NB 4

// ws layout in 4-byte words:
// [0,96)        counts (int)
// [96,1632)     sums (float)    N*C*E
// [1632,3168)   means (float)   N*C*E
// [3168,3172)   reg per n
// [3172,3176)   triplet per n
// [3176,3180)   varsum per n
#define WS_WORDS 3180

__global__ __launch_bounds__(256) void k_zero(int* ws) {
    for (int i = threadIdx.x; i < WS_WORDS; i += 256) ws[i] = 0;
}

// Round-5 k_accum: (a) all 16 channel loads staged in registers (launch_bounds
// (256,4) -> VGPR cap 128, live ~90, no spill) so 16 loads are in flight per
// wave; (b) 4x quarter-wave-private LDS histograms to cut same-address
// ds_add_f32 serialization from ~7-way to ~2-3-way (replicas of one (c,e)
// land in banks +0/+24/+16/+8: 408 % 32 = 24).
__global__ __launch_bounds__(256, 4) void k_accum(const float* __restrict__ in,
                                                  const int* __restrict__ tgt,
                                                  float* __restrict__ sums,
                                                  int* __restrict__ counts) {
    const int n = blockIdx.y;
    const int tid = threadIdx.x;
    __shared__ float ls[4][C_LAB][EDIM + 1];
    __shared__ int lc[4][C_LAB];
    for (int i = tid; i < 4 * C_LAB * (EDIM + 1); i += 256) (&ls[0][0][0])[i] = 0.f;
    if (tid < 4 * C_LAB) (&lc[0][0])[tid] = 0;
    __syncthreads();

    const int rep = (tid >> 4) & 3;  // quarter-wave replica id
    const size_t p0 = (size_t)(blockIdx.x * 256 + tid) * 4;
    const float* bp = in + (size_t)n * EDIM * PPIX + p0;
    const int4 lab = *reinterpret_cast<const int4*>(tgt + (size_t)n * PPIX + p0);

    float4 x[EDIM];
#pragma unroll
    for (int e = 0; e < EDIM; ++e)
        x[e] = *reinterpret_cast<const float4*>(bp + (size_t)e * PPIX);

    atomicAdd(&lc[rep][lab.x], 1);
    atomicAdd(&lc[rep][lab.y], 1);
    atomicAdd(&lc[rep][lab.z], 1);
    atomicAdd(&lc[rep][lab.w], 1);

#pragma unroll
    for (int e = 0; e < EDIM; ++e) {
        atomicAdd(&ls[rep][lab.x][e], x[e].x);
        atomicAdd(&ls[rep][lab.y][e], x[e].y);
        atomicAdd(&ls[rep][lab.z][e], x[e].z);
        atomicAdd(&ls[rep][lab.w][e], x[e].w);
    }
    __syncthreads();

    for (int i = tid; i < C_LAB * EDIM; i += 256) {
        const int c = i >> 4, e = i & 15;
        const float s = ls[0][c][e] + ls[1][c][e] + ls[2][c][e] + ls[3][c][e];
        atomicAdd(&sums[((size_t)n * C_LAB + c) * EDIM + e], s);
    }
    if (tid < C_LAB)
        atomicAdd(&counts[n * C_LAB + tid],
                  lc[0][tid] + lc[1][tid] + lc[2][tid] + lc[3][tid]);
}

__global__ __launch_bounds__(128) void k_means(const float* __restrict__ sums,
                                               const int* __restrict__ counts,
                                               float* __restrict__ means,
                                               float* __restrict__ regv) {
    const int t = threadIdx.x;
    if (t >= NB * C_LAB) return;
    const int n = t / C_LAB;
    const float inv = 1.f / (float)counts[t];
    float s2 = 0.f;
#pragma unroll
    for (int e = 0; e < EDIM; ++e) {
        float m = sums[t * EDIM + e] * inv;
        means[t * EDIM + e] = m;
        s2 += m * m;
    }
    float d = sqrtf(s2) - 1.f;
    atomicAdd(&regv[n], d * d);
}

__global__ __launch_bounds__(256) void k_triplet(const float* __restrict__ means,
                                                 const int* __restrict__ eattr,
                                                 const int* __restrict__ erep,
                                                 float* __restrict__ tripv) {
    const int n = blockIdx.x;
    const int tid = threadIdx.x;
    __shared__ float cm[C_LAB][EDIM];
    __shared__ float dA[200], dR[200];
    __shared__ int a0[200], a1[200], r0[200], r1[200];
    for (int i = tid; i < C_LAB * EDIM; i += 256)
        (&cm[0][0])[i] = means[n * C_LAB * EDIM + i];
    __syncthreads();
    if (tid < 200) {
        int i0 = eattr[n * 400 + tid], i1 = eattr[n * 400 + 200 + tid];
        a0[tid] = i0; a1[tid] = i1;
        float s = 0.f;
#pragma unroll
        for (int e = 0; e < EDIM; ++e) {
            float d = cm[i0][e] - cm[i1][e] + 1e-6f;
            s += d * d;
        }
        dA[tid] = s;
        i0 = erep[n * 400 + tid]; i1 = erep[n * 400 + 200 + tid];
        r0[tid] = i0; r1[tid] = i1;
        s = 0.f;
#pragma unroll
        for (int e = 0; e < EDIM; ++e) {
            float d = cm[i0][e] - cm[i1][e] + 1e-6f;
            s += d * d;
        }
        dR[tid] = s;
    }
    __syncthreads();

    float sum = 0.f;
    int cnt = 0;
    for (int idx = tid; idx < 200 * 200; idx += 256) {
        const int a = idx / 200;
        const int r = idx - a * 200;
        const int m = (a0[a] == r0[r]) + (a0[a] == r1[r]) +
                      (a1[a] == r0[r]) + (a1[a] == r1[r]);
        const float t = 0.5f * (dA[a] - dR[r]) + 0.01f;
        if (m == 1 && t > 0.f) { sum += t; cnt++; }
    }
    for (int o = 32; o; o >>= 1) {
        sum += __shfl_down(sum, o, 64);
        cnt += __shfl_down(cnt, o, 64);
    }
    __shared__ float rs[4];
    __shared__ int rc[4];
    if ((tid & 63) == 0) { rs[tid >> 6] = sum; rc[tid >> 6] = cnt; }
    __syncthreads();
    if (tid == 0) {
        float S = rs[0] + rs[1] + rs[2] + rs[3];
        int Cn = rc[0] + rc[1] + rc[2] + rc[3];
        tripv[n] = (Cn > 0) ? S / (float)Cn : 0.f;
    }
}

// Round-5 k_var: register-staged x[16] (MLP fix) under (256,4); no atomics in
// the hot path, scattered lm reads are plain ds_read (cheap per m136).
__global__ __launch_bounds__(256, 4) void k_var(const float* __restrict__ in,
                                                const int* __restrict__ tgt,
                                                const float* __restrict__ means,
                                                const int* __restrict__ counts,
                                                float* __restrict__ varv) {
    const int n = blockIdx.y;
    const int tid = threadIdx.x;
    __shared__ float lm[C_LAB][EDIM + 1];
    __shared__ float licnt[C_LAB];
    for (int i = tid; i < C_LAB * EDIM; i += 256) {
        const int c = i >> 4, e = i & 15;
        lm[c][e] = means[(size_t)n * C_LAB * EDIM + i];
    }
    if (tid < C_LAB) licnt[tid] = 1.f / (float)counts[n * C_LAB + tid];
    __syncthreads();

    const size_t p0 = (size_t)(blockIdx.x * 256 + tid) * 4;
    const float* bp = in + (size_t)n * EDIM * PPIX + p0;
    const int4 lab = *reinterpret_cast<const int4*>(tgt + (size_t)n * PPIX + p0);

    float4 x[EDIM];
#pragma unroll
    for (int e = 0; e < EDIM; ++e)
        x[e] = *reinterpret_cast<const float4*>(bp + (size_t)e * PPIX);

    float d0 = 0.f, d1 = 0.f, d2 = 0.f, d3 = 0.f;
#pragma unroll
    for (int e = 0; e < EDIM; ++e) {
        float t0 = x[e].x - lm[lab.x][e];
        float t1 = x[e].y - lm[lab.y][e];
        float t2 = x[e].z - lm[lab.z][e];
        float t3 = x[e].w - lm[lab.w][e];
        d0 += t0 * t0;
        d1 += t1 * t1;
        d2 += t2 * t2;
        d3 += t3 * t3;
    }

    float h0 = fmaxf(sqrtf(d0) - 0.5f, 0.f);
    float h1 = fmaxf(sqrtf(d1) - 0.5f, 0.f);
    float h2 = fmaxf(sqrtf(d2) - 0.5f, 0.f);
    float h3 = fmaxf(sqrtf(d3) - 0.5f, 0.f);
    float acc = h0 * h0 * licnt[lab.x] + h1 * h1 * licnt[lab.y] +
                h2 * h2 * licnt[lab.z] + h3 * h3 * licnt[lab.w];

    for (int o = 32; o; o >>= 1) acc += __shfl_down(acc, o, 64);
    __shared__ float rs[4];
    if ((tid & 63) == 0) rs[tid >> 6] = acc;
    __syncthreads();
    if (tid == 0) atomicAdd(&varv[n], rs[0] + rs[1] + rs[2] + rs[3]);
}

__global__ void k_final(const float* __restrict__ varv,
                        const float* __restrict__ tripv,
                        const float* __restrict__ regv,
                        float* __restrict__ out) {
    float s = 0.f;
#pragma unroll
    for (int n = 0; n < NB; ++n)
        s += varv[n] / (float)C_LAB + tripv[n] + regv[n] / (float)C_LAB;
    out[0] = s / (float)(NB * NB);
}

extern "C" void kernel_launch(void* const* d_in, const int* in_sizes, int n_in,
                              void* d_out, int out_size, void* d_ws, size_t ws_size,
                              hipStream_t stream) {
    const float* input = (const float*)d_in[0];
    const int* target = (const int*)d_in[1];
    const int* eattr = (const int*)d_in[2];
    const int* erep = (const int*)d_in[3];
    float* out = (float*)d_out;

    int* counts = (int*)d_ws;
    float* wsf = (float*)d_ws;
    float* sums = wsf + 96;
    float* means = wsf + 1632;
    float* regv = wsf + 3168;
    float* tripv = wsf + 3172;
    float* varv = wsf + 3176;

    k_zero<<<1, 256, 0, stream>>>((int*)d_ws);

    dim3 grid(PPIX / (256 * 4), NB);  // 576 x 4
    k_accum<<<grid, 256, 0, stream>>>(input, target, sums, counts);
    k_means<<<1, 128, 0, stream>>>(sums, counts, means, regv);
    k_triplet<<<NB, 256, 0, stream>>>(means, eattr, erep, tripv);
    k_var<<<grid, 256, 0, stream>>>(input, target, means, counts, varv);
    k_final<<<1, 1, 0, stream>>>(varv, tripv, regv, out);
}